// Round 10
// baseline (38.859 us; speedup 1.0000x reference)
//
#include <hip/hip_runtime.h>
#include <hip/hip_bf16.h>

#define NEG_SLOPE 0.01f

// Shapes (fixed by the reference setup): B=16, N=1024, D=256.
#define B_DIM 16
#define N_DIM 1024
#define D_DIM 256
#define ROWS (B_DIM * N_DIM)   // 16384

typedef float fvec4 __attribute__((ext_vector_type(4)));

__device__ __forceinline__ float wave_reduce_sum(float v) {
#pragma unroll
    for (int off = 32; off > 0; off >>= 1) v += __shfl_xor(v, off, 64);
    return v;
}

// ATTRIBUTION ROUND: kernels identical to R9's (the 22.4 us plateau config).
// Each kernel is launched TWICE (idempotent: identical rewrites of the same
// buffers; deterministic; final output unchanged). With baseline
//   22.4 = T_fixed + T_k1 + T_k2,
// this round measures  dur = T_fixed + 2*T_k1 + 2*T_k2, so
//   T_fixed = 2*22.4 - dur,   T_k1 + T_k2 = dur - 22.4.

__global__ __launch_bounds__(256) void qk_kernel(const float* __restrict__ i_em,
                                                 const float* __restrict__ a_w,
                                                 const float* __restrict__ a_b,
                                                 float* __restrict__ qb,
                                                 float* __restrict__ k) {
    const int wid  = threadIdx.x >> 6;
    const int lane = threadIdx.x & 63;
    const int row0 = blockIdx.x * 16 + wid * 4;

    const float4 wq = *reinterpret_cast<const float4*>(a_w + lane * 4);
    const float4 wk = *reinterpret_cast<const float4*>(a_w + D_DIM + lane * 4);
    const float bias = a_b[0];

    float4 e[4];
#pragma unroll
    for (int r = 0; r < 4; ++r)
        e[r] = *reinterpret_cast<const float4*>(i_em + (size_t)(row0 + r) * D_DIM + lane * 4);

    float sq[4], sk[4];
#pragma unroll
    for (int r = 0; r < 4; ++r) {
        sq[r] = e[r].x * wq.x + e[r].y * wq.y + e[r].z * wq.z + e[r].w * wq.w;
        sk[r] = e[r].x * wk.x + e[r].y * wk.y + e[r].z * wk.z + e[r].w * wk.w;
    }
#pragma unroll
    for (int r = 0; r < 4; ++r) {
        sq[r] = wave_reduce_sum(sq[r]);
        sk[r] = wave_reduce_sum(sk[r]);
    }

    if (lane == 0) {
        fvec4 vq = {sq[0] + bias, sq[1] + bias, sq[2] + bias, sq[3] + bias};
        fvec4 vk = {sk[0], sk[1], sk[2], sk[3]};
        *reinterpret_cast<fvec4*>(qb + row0) = vq;
        *reinterpret_cast<fvec4*>(k + row0)  = vk;
    }
}

__global__ __launch_bounds__(256) void softmax_kernel(const float* __restrict__ qb,
                                                      const float* __restrict__ k,
                                                      float* __restrict__ out) {
    const int wid  = threadIdx.x >> 6;
    const int lane = threadIdx.x & 63;
    const int row0 = blockIdx.x * 8 + wid * 2;
    const int b    = row0 >> 10;

    const float4* k4 = reinterpret_cast<const float4*>(k + b * N_DIM);
    float4 kv[4];
#pragma unroll
    for (int c = 0; c < 4; ++c) kv[c] = k4[c * 64 + lane];

#pragma unroll
    for (int r = 0; r < 2; ++r) {
        const int row = row0 + r;
        const float qi = qb[row];

        float e[4][4];
        float s = 0.0f;
#pragma unroll
        for (int c = 0; c < 4; ++c) {
            float v0 = qi + kv[c].x; v0 = (v0 >= 0.0f) ? v0 : NEG_SLOPE * v0;
            float v1 = qi + kv[c].y; v1 = (v1 >= 0.0f) ? v1 : NEG_SLOPE * v1;
            float v2 = qi + kv[c].z; v2 = (v2 >= 0.0f) ? v2 : NEG_SLOPE * v2;
            float v3 = qi + kv[c].w; v3 = (v3 >= 0.0f) ? v3 : NEG_SLOPE * v3;
            e[c][0] = __expf(v0);
            e[c][1] = __expf(v1);
            e[c][2] = __expf(v2);
            e[c][3] = __expf(v3);
            s += (e[c][0] + e[c][1]) + (e[c][2] + e[c][3]);
        }
        s = wave_reduce_sum(s);
        const float inv = __builtin_amdgcn_rcpf(s);

        fvec4* o4 = reinterpret_cast<fvec4*>(out + (size_t)row * N_DIM);
#pragma unroll
        for (int c = 0; c < 4; ++c) {
            fvec4 o;
            o.x = e[c][0] * inv;
            o.y = e[c][1] * inv;
            o.z = e[c][2] * inv;
            o.w = e[c][3] * inv;
            __builtin_nontemporal_store(o, &o4[c * 64 + lane]);
        }
    }
}

extern "C" void kernel_launch(void* const* d_in, const int* in_sizes, int n_in,
                              void* d_out, int out_size, void* d_ws, size_t ws_size,
                              hipStream_t stream) {
    const float* i_em = (const float*)d_in[0];
    const float* a_w  = (const float*)d_in[1];
    const float* a_b  = (const float*)d_in[2];
    float* out = (float*)d_out;

    float* qb = (float*)d_ws;              // ROWS floats (bias folded in)
    float* k  = qb + ROWS;                 // ROWS floats

    // Each kernel twice: idempotent, deterministic, same final output.
    qk_kernel<<<ROWS / 16, 256, 0, stream>>>(i_em, a_w, a_b, qb, k);
    qk_kernel<<<ROWS / 16, 256, 0, stream>>>(i_em, a_w, a_b, qb, k);
    softmax_kernel<<<ROWS / 8, 256, 0, stream>>>(qb, k, out);
    softmax_kernel<<<ROWS / 8, 256, 0, stream>>>(qb, k, out);
}